// Round 1
// baseline (520.326 us; speedup 1.0000x reference)
//
#include <hip/hip_runtime.h>
#include <hip/hip_bf16.h>

typedef __attribute__((ext_vector_type(8))) short s16x8;
typedef __attribute__((ext_vector_type(4))) float f32x4;

__device__ __forceinline__ unsigned short f2bf(float x) {
    unsigned int u = __float_as_uint(x);
    u += 0x7fffu + ((u >> 16) & 1u);          // round-to-nearest-even
    return (unsigned short)(u >> 16);
}

// ---------------- prep: convert weights to bf16 into ws ----------------
__global__ void prep_kernel(const float* __restrict__ W_cat,
                            const float* __restrict__ W_ih,
                            const float* __restrict__ W_hh,
                            unsigned short* __restrict__ wcat,
                            unsigned short* __restrict__ wih,
                            unsigned short* __restrict__ whh) {
    int stride = gridDim.x * blockDim.x;
    const int TOT = 256*256 + 2*768*256;
    for (int i = blockIdx.x * blockDim.x + threadIdx.x; i < TOT; i += stride) {
        if (i < 256*256) {
            int j = i >> 8, k = i & 255;
            wcat[i] = f2bf(W_cat[j*257 + k]);          // drop the amount column
        } else if (i < 256*256 + 768*256) {
            int t = i - 256*256;
            wih[t] = f2bf(W_ih[t]);
        } else {
            int t = i - 256*256 - 768*256;
            whh[t] = f2bf(W_hh[t]);
        }
    }
}

// ---------------- copy memory + last_update to output ----------------
__global__ void copy_kernel(const float4* __restrict__ mem,
                            const float4* __restrict__ lu,
                            float4* __restrict__ out_mem,
                            float4* __restrict__ out_lu,
                            long n_mem4, long n_lu4) {
    long stride = (long)gridDim.x * blockDim.x;
    long total = n_mem4 + n_lu4;
    for (long i = blockIdx.x * (long)blockDim.x + threadIdx.x; i < total; i += stride) {
        if (i < n_mem4) out_mem[i] = mem[i];
        else            out_lu[i - n_mem4] = lu[i - n_mem4];
    }
}

__global__ void scatter_lu_kernel(const int* __restrict__ ids,
                                  const float* __restrict__ ts,
                                  float* __restrict__ out_lu, int M) {
    int i = blockIdx.x * blockDim.x + threadIdx.x;
    if (i < M) out_lu[ids[i]] = ts[i];
}

// ---------------- x = bf16(msgs @ Wcat^T + amt*wamt + b_cat) ----------------
__global__ __launch_bounds__(512, 2)
void xgemm_kernel(const float* __restrict__ msgs,          // [M,256] f32
                  const float* __restrict__ amt,           // [M]
                  const float* __restrict__ b_cat,         // [256]
                  const float* __restrict__ W_cat,         // [256,257] f32 (amount col)
                  const unsigned short* __restrict__ wcat, // [256,256] bf16
                  unsigned short* __restrict__ xout,       // [M,256] bf16
                  int M) {
    __shared__ char smsg[128*128];   // [row][128B] swizzled bf16 K-slice
    __shared__ char swt [256*128];

    int tid = threadIdx.x;
    int lane = tid & 63;
    int w = tid >> 6;
    int wr = w >> 2, wc = w & 3;     // wave = 64 rows x 64 cols
    int m0 = blockIdx.x * 128;

    f32x4 acc[4][4];
    #pragma unroll
    for (int a = 0; a < 4; ++a)
        #pragma unroll
        for (int b = 0; b < 4; ++b) acc[a][b] = (f32x4){0.f, 0.f, 0.f, 0.f};

    for (int ks = 0; ks < 4; ++ks) {
        int k0 = ks * 64;
        // stage msg slice [128 rows][64 bf16], f32->bf16: 1024 16B-chunks
        #pragma unroll
        for (int it = 0; it < 2; ++it) {
            int q = tid + it * 512;
            int row = q >> 3, part = q & 7;
            int grow = min(m0 + row, M - 1);
            const float4* src = (const float4*)(msgs + (size_t)grow * 256 + k0 + part * 8);
            float4 a = src[0], b = src[1];
            s16x8 v = { (short)f2bf(a.x), (short)f2bf(a.y), (short)f2bf(a.z), (short)f2bf(a.w),
                        (short)f2bf(b.x), (short)f2bf(b.y), (short)f2bf(b.z), (short)f2bf(b.w) };
            *(s16x8*)(smsg + row * 128 + ((part ^ (row & 7)) * 16)) = v;
        }
        // stage Wcat slice [256 rows][64 bf16]: 2048 chunks
        #pragma unroll
        for (int it = 0; it < 4; ++it) {
            int q = tid + it * 512;
            int row = q >> 3, part = q & 7;
            s16x8 v = *(const s16x8*)((const char*)wcat + (size_t)row * 512 + k0 * 2 + part * 16);
            *(s16x8*)(swt + row * 128 + ((part ^ (row & 7)) * 16)) = v;
        }
        __syncthreads();
        #pragma unroll
        for (int c = 0; c < 2; ++c) {
            int p = c * 4 + (lane >> 4);
            s16x8 af[4], bf[4];
            #pragma unroll
            for (int mf = 0; mf < 4; ++mf) {
                int row = wr * 64 + mf * 16 + (lane & 15);
                af[mf] = *(const s16x8*)(smsg + row * 128 + ((p ^ (row & 7)) * 16));
            }
            #pragma unroll
            for (int nf = 0; nf < 4; ++nf) {
                int row = wc * 64 + nf * 16 + (lane & 15);
                bf[nf] = *(const s16x8*)(swt + row * 128 + ((p ^ (row & 7)) * 16));
            }
            #pragma unroll
            for (int mf = 0; mf < 4; ++mf)
                #pragma unroll
                for (int nf = 0; nf < 4; ++nf)
                    acc[mf][nf] = __builtin_amdgcn_mfma_f32_16x16x32_bf16(
                        af[mf], bf[nf], acc[mf][nf], 0, 0, 0);
        }
        __syncthreads();
    }
    // epilogue: + b_cat + amt*wamt, cast bf16, store
    #pragma unroll
    for (int nf = 0; nf < 4; ++nf) {
        int col = wc * 64 + nf * 16 + (lane & 15);
        float bc = b_cat[col];
        float wa = W_cat[col * 257 + 256];
        #pragma unroll
        for (int mf = 0; mf < 4; ++mf) {
            int rbase = m0 + wr * 64 + mf * 16 + ((lane >> 4) * 4);
            #pragma unroll
            for (int r = 0; r < 4; ++r) {
                int row = rbase + r;
                if (row < M) {
                    float v = acc[mf][nf][r] + bc + amt[row] * wa;
                    xout[(size_t)row * 256 + col] = f2bf(v);
                }
            }
        }
    }
}

// ---------------- fused GRU: gi/gh GEMM + gates + scatter ----------------
// grid.x = mtiles*4 : (blockIdx>>2)=row tile of 128, (blockIdx&3)=64-col chunk
__global__ __launch_bounds__(512, 2)
void gru_kernel(const int* __restrict__ ids,
                const unsigned short* __restrict__ xin,  // [M,256] bf16
                const float* __restrict__ memory,        // [N,256] f32
                const unsigned short* __restrict__ wih,  // [768,256] bf16
                const unsigned short* __restrict__ whh,  // [768,256] bf16
                const float* __restrict__ b_ih,
                const float* __restrict__ b_hh,
                float* __restrict__ out_mem,
                int M) {
    extern __shared__ char lds[];
    char* sx = lds;                      // 16384: x slice  [128][64 bf16] swizzled
    char* sh = lds + 16384;              // 16384: h slice
    char* sw = lds + 32768;              // 49152: W panels [384][64 bf16]
    int* sids = (int*)(lds + 81920);     // 512:   gathered node ids

    int tid = threadIdx.x;
    int lane = tid & 63;
    int w = tid >> 6;
    int wr = w >> 2, wc = w & 3;         // wave = 64 rows x 16 cols
    int nc = blockIdx.x & 3;
    int m0 = (blockIdx.x >> 2) * 128;

    if (tid < 128) sids[tid] = ids[min(m0 + tid, M - 1)];
    __syncthreads();

    f32x4 acc[6][4];                     // [panel: ir,iz,in,hr,hz,hn][mfrag]
    #pragma unroll
    for (int pn = 0; pn < 6; ++pn)
        #pragma unroll
        for (int mf = 0; mf < 4; ++mf) acc[pn][mf] = (f32x4){0.f, 0.f, 0.f, 0.f};

    for (int ks = 0; ks < 4; ++ks) {
        int k0 = ks * 64;
        // stage x slice (bf16 copy): 1024 chunks
        #pragma unroll
        for (int it = 0; it < 2; ++it) {
            int q = tid + it * 512;
            int row = q >> 3, part = q & 7;
            int grow = min(m0 + row, M - 1);
            s16x8 v = *(const s16x8*)((const char*)xin + (size_t)grow * 512 + k0 * 2 + part * 16);
            *(s16x8*)(sx + row * 128 + ((part ^ (row & 7)) * 16)) = v;
        }
        // stage h slice (gather f32 -> bf16): 1024 chunks
        #pragma unroll
        for (int it = 0; it < 2; ++it) {
            int q = tid + it * 512;
            int row = q >> 3, part = q & 7;
            int gid = sids[row];
            const float4* src = (const float4*)(memory + (size_t)gid * 256 + k0 + part * 8);
            float4 a = src[0], b = src[1];
            s16x8 v = { (short)f2bf(a.x), (short)f2bf(a.y), (short)f2bf(a.z), (short)f2bf(a.w),
                        (short)f2bf(b.x), (short)f2bf(b.y), (short)f2bf(b.z), (short)f2bf(b.w) };
            *(s16x8*)(sh + row * 128 + ((part ^ (row & 7)) * 16)) = v;
        }
        // stage 6 weight panels [64 rows each][64 bf16]: 3072 chunks
        #pragma unroll
        for (int it = 0; it < 6; ++it) {
            int q = tid + it * 512;
            int row = q >> 3, part = q & 7;          // row 0..383
            int pn = row >> 6, r = row & 63;
            int gate = (pn < 3) ? pn : pn - 3;
            const unsigned short* src = (pn < 3) ? wih : whh;
            s16x8 v = *(const s16x8*)((const char*)src +
                        ((size_t)(gate * 256 + nc * 64 + r)) * 512 + k0 * 2 + part * 16);
            *(s16x8*)(sw + row * 128 + ((part ^ (row & 7)) * 16)) = v;
        }
        __syncthreads();
        #pragma unroll
        for (int c = 0; c < 2; ++c) {
            int p = c * 4 + (lane >> 4);
            s16x8 ax[4], ah[4], bw[6];
            #pragma unroll
            for (int mf = 0; mf < 4; ++mf) {
                int row = wr * 64 + mf * 16 + (lane & 15);
                int off = row * 128 + ((p ^ (row & 7)) * 16);
                ax[mf] = *(const s16x8*)(sx + off);
                ah[mf] = *(const s16x8*)(sh + off);
            }
            #pragma unroll
            for (int pn = 0; pn < 6; ++pn) {
                int row = pn * 64 + wc * 16 + (lane & 15);
                int off = row * 128 + ((p ^ (row & 7)) * 16);
                bw[pn] = *(const s16x8*)(sw + off);
            }
            #pragma unroll
            for (int pn = 0; pn < 6; ++pn)
                #pragma unroll
                for (int mf = 0; mf < 4; ++mf)
                    acc[pn][mf] = __builtin_amdgcn_mfma_f32_16x16x32_bf16(
                        (pn < 3) ? ax[mf] : ah[mf], bw[pn], acc[pn][mf], 0, 0, 0);
        }
        __syncthreads();
    }

    // epilogue: gates + blend + scatter store
    int colL = wc * 16 + (lane & 15);
    int col = nc * 64 + colL;                        // 0..255 within gate
    float bir = b_ih[col], biz = b_ih[256 + col], bin = b_ih[512 + col];
    float bhr = b_hh[col], bhz = b_hh[256 + col], bhn = b_hh[512 + col];
    #pragma unroll
    for (int mf = 0; mf < 4; ++mf) {
        int rb = wr * 64 + mf * 16 + (lane >> 4) * 4;
        #pragma unroll
        for (int r = 0; r < 4; ++r) {
            int rl = rb + r;
            if (m0 + rl < M) {
                int gid = sids[rl];
                float hv = memory[(size_t)gid * 256 + col];
                float ir = acc[0][mf][r] + bir;
                float iz = acc[1][mf][r] + biz;
                float in_ = acc[2][mf][r] + bin;
                float hr = acc[3][mf][r] + bhr;
                float hz = acc[4][mf][r] + bhz;
                float hn = acc[5][mf][r] + bhn;
                float rg = 1.f / (1.f + __expf(-(ir + hr)));
                float zg = 1.f / (1.f + __expf(-(iz + hz)));
                float ng = tanhf(in_ + rg * hn);
                out_mem[(size_t)gid * 256 + col] = (1.f - zg) * ng + zg * hv;
            }
        }
    }
}

extern "C" void kernel_launch(void* const* d_in, const int* in_sizes, int n_in,
                              void* d_out, int out_size, void* d_ws, size_t ws_size,
                              hipStream_t stream) {
    const int*   ids   = (const int*)  d_in[0];
    const float* msgs  = (const float*)d_in[1];
    const float* ts    = (const float*)d_in[2];
    const float* amt   = (const float*)d_in[3];
    const float* mem   = (const float*)d_in[4];
    const float* lu    = (const float*)d_in[5];
    const float* W_cat = (const float*)d_in[6];
    const float* b_cat = (const float*)d_in[7];
    const float* W_ih  = (const float*)d_in[8];
    const float* W_hh  = (const float*)d_in[9];
    const float* b_ih  = (const float*)d_in[10];
    const float* b_hh  = (const float*)d_in[11];

    int M = in_sizes[0];                 // 100000 updates
    int N = in_sizes[5];                 // 500000 nodes

    float* out_mem = (float*)d_out;
    float* out_lu  = out_mem + (size_t)N * 256;

    // ws layout: bf16 weights (~0.9 MB), then x_bf16 at 1 MB (~51.2 MB)
    unsigned short* wcat = (unsigned short*)d_ws;
    unsigned short* wih  = wcat + 256 * 256;
    unsigned short* whh  = wih + 768 * 256;
    unsigned short* xbf  = (unsigned short*)((char*)d_ws + (1 << 20));

    prep_kernel<<<256, 256, 0, stream>>>(W_cat, W_ih, W_hh, wcat, wih, whh);

    long n_mem4 = (long)N * 64, n_lu4 = N / 4;
    copy_kernel<<<2048, 256, 0, stream>>>((const float4*)mem, (const float4*)lu,
                                          (float4*)out_mem, (float4*)out_lu,
                                          n_mem4, n_lu4);
    scatter_lu_kernel<<<(M + 255) / 256, 256, 0, stream>>>(ids, ts, out_lu, M);

    int mtiles = (M + 127) / 128;
    xgemm_kernel<<<mtiles, 512, 0, stream>>>(msgs, amt, b_cat, W_cat, wcat, xbf, M);

    (void)hipFuncSetAttribute(reinterpret_cast<const void*>(gru_kernel),
                              hipFuncAttributeMaxDynamicSharedMemorySize, 82432);
    gru_kernel<<<mtiles * 4, 512, 82432, stream>>>(ids, xbf, mem, wih, whh,
                                                   b_ih, b_hh, out_mem, M);
}

// Round 2
// 454.782 us; speedup vs baseline: 1.1441x; 1.1441x over previous
//
#include <hip/hip_runtime.h>
#include <hip/hip_bf16.h>

typedef __attribute__((ext_vector_type(8))) short s16x8;
typedef __attribute__((ext_vector_type(4))) float f32x4;

__device__ __forceinline__ unsigned short f2bf(float x) {
    unsigned int u = __float_as_uint(x);
    u += 0x7fffu + ((u >> 16) & 1u);          // round-to-nearest-even
    return (unsigned short)(u >> 16);
}
__device__ __forceinline__ float bf2f(unsigned short h) {
    return __uint_as_float((unsigned int)h << 16);
}
// global -> LDS DMA, 16B per lane. LDS dst must be wave-uniform (HW adds lane*16).
__device__ __forceinline__ void gload_lds16(const void* g, void* l) {
    __builtin_amdgcn_global_load_lds(
        (const __attribute__((address_space(1))) void*)g,
        (__attribute__((address_space(3))) void*)(unsigned int)(size_t)l,
        16, 0, 0);
}

// ---------------- prep_w: fold W_cat into W_ih; bf16 weights ----------------
// wm = W_ih @ W_cat[:, :256]  (bf16 [768][256])
// whh = bf16(W_hh)            ([768][256])
// wamt = W_ih @ W_cat[:,256]  (f32 [768])
// bcomb = W_ih @ b_cat + b_ih (f32 [768])
__global__ void prep_w_kernel(const float* __restrict__ W_cat,
                              const float* __restrict__ b_cat,
                              const float* __restrict__ W_ih,
                              const float* __restrict__ W_hh,
                              const float* __restrict__ b_ih,
                              unsigned short* __restrict__ wm,
                              unsigned short* __restrict__ whh,
                              float* __restrict__ wamt,
                              float* __restrict__ bcomb) {
    int idx = blockIdx.x * blockDim.x + threadIdx.x;
    const int NW = 768 * 256;
    if (idx < NW) {
        int g = idx >> 8, c = idx & 255;
        float s = 0.f;
        #pragma unroll 4
        for (int k = 0; k < 256; ++k) s += W_ih[g * 256 + k] * W_cat[k * 257 + c];
        wm[idx] = f2bf(s);
    } else if (idx < 2 * NW) {
        int t = idx - NW;
        whh[t] = f2bf(W_hh[t]);
    } else if (idx < 2 * NW + 768) {
        int g = idx - 2 * NW;
        float sa = 0.f, sb = 0.f;
        for (int k = 0; k < 256; ++k) {
            float w = W_ih[g * 256 + k];
            sa += w * W_cat[k * 257 + 256];
            sb += w * b_cat[k];
        }
        wamt[g] = sa;
        bcomb[g] = sb + b_ih[g];
    }
}

// ---------------- prep_msgs: msgs -> bf16; plus lu bulk copy ----------------
__global__ void prep_msgs_kernel(const float* __restrict__ msgs,
                                 unsigned short* __restrict__ mbf,
                                 const float* __restrict__ lu,
                                 float* __restrict__ out_lu,
                                 long mchunks, long luchunks) {
    long stride = (long)gridDim.x * blockDim.x;
    long total = mchunks + luchunks;
    for (long i = blockIdx.x * (long)blockDim.x + threadIdx.x; i < total; i += stride) {
        if (i < mchunks) {
            const float4* s = (const float4*)(msgs + i * 8);
            float4 a = s[0], b = s[1];
            s16x8 v = { (short)f2bf(a.x), (short)f2bf(a.y), (short)f2bf(a.z), (short)f2bf(a.w),
                        (short)f2bf(b.x), (short)f2bf(b.y), (short)f2bf(b.z), (short)f2bf(b.w) };
            *(s16x8*)(mbf + i * 8) = v;
        } else {
            long j = i - mchunks;
            ((float4*)out_lu)[j] = ((const float4*)lu)[j];
        }
    }
}

__global__ void build_inv_kernel(const int* __restrict__ ids, int* __restrict__ inv, int M) {
    int i = blockIdx.x * blockDim.x + threadIdx.x;
    if (i < M) inv[ids[i]] = i + 1;
}

// ---------------- copy + gather: one wave per 1KB row ----------------
// inv[row]==0: copy row to out.  else: (HBF) divert row as bf16 to hbf[inv-1]; skip out write.
template<bool HBF>
__global__ void copy_gather_kernel(const float* __restrict__ memory,
                                   const int* __restrict__ inv,
                                   float* __restrict__ out_mem,
                                   unsigned short* __restrict__ hbf,
                                   int N) {
    int wave = (blockIdx.x * blockDim.x + threadIdx.x) >> 6;
    int lane = threadIdx.x & 63;
    int nw = (gridDim.x * blockDim.x) >> 6;
    for (int row = wave; row < N; row += nw) {
        int iv = inv[row];
        if (iv == 0) {
            float4 v = ((const float4*)(memory + (size_t)row * 256))[lane];
            ((float4*)(out_mem + (size_t)row * 256))[lane] = v;
        } else if (HBF) {
            float4 v = ((const float4*)(memory + (size_t)row * 256))[lane];
            ushort4 o = { f2bf(v.x), f2bf(v.y), f2bf(v.z), f2bf(v.w) };
            *(ushort4*)(hbf + (size_t)(iv - 1) * 256 + lane * 4) = o;
        }
    }
}

// ---------------- fused GRU ----------------
// A-slices (rows of mbf/hbf) and 6 weight panels staged per 64-K chunk via
// global_load_lds w16, pre-swizzled per-lane global addr (XOR row&7 on 16B parts).
// Full double-buffer (160KB LDS), prefetch next chunk before compute (T3-min).
__device__ __forceinline__ void stage_dma_a(const unsigned short* __restrict__ base,
                                            int m0, int M, int k0, char* ldsbuf, int tid) {
    #pragma unroll
    for (int it = 0; it < 2; ++it) {
        int q = tid + it * 512;
        int row = q >> 3;
        int part = (q & 7) ^ (row & 7);
        int grow = m0 + row; if (grow >= M) grow = M - 1;
        gload_lds16((const char*)base + (size_t)grow * 512 + k0 * 2 + part * 16,
                    ldsbuf + (tid & ~63) * 16 + it * 8192);
    }
}
__device__ __forceinline__ void stage_dma_w(const unsigned short* __restrict__ wm,
                                            const unsigned short* __restrict__ whh,
                                            int nc, int k0, char* swbuf, int tid) {
    #pragma unroll
    for (int it = 0; it < 6; ++it) {
        int q = tid + it * 512;
        int r = q >> 3;
        int part = (q & 7) ^ (r & 7);
        int pn = r >> 6, rr = r & 63;
        const unsigned short* src = (pn < 3)
            ? wm  + ((size_t)(pn * 256 + nc * 64 + rr)) * 256
            : whh + ((size_t)((pn - 3) * 256 + nc * 64 + rr)) * 256;
        gload_lds16((const char*)src + k0 * 2 + part * 16,
                    swbuf + (tid & ~63) * 16 + it * 8192);
    }
}
// fallback h staging: reg gather f32 -> bf16 -> swizzled ds_write
__device__ __forceinline__ void stage_reg_h(const int* __restrict__ ids,
                                            const float* __restrict__ memory,
                                            int m0, int M, int k0, char* shbuf, int tid) {
    #pragma unroll
    for (int it = 0; it < 2; ++it) {
        int q = tid + it * 512;
        int row = q >> 3, part = q & 7;
        int grow = m0 + row; if (grow >= M) grow = M - 1;
        int gid = ids[grow];
        const float4* src = (const float4*)(memory + (size_t)gid * 256 + k0 + part * 8);
        float4 a = src[0], b = src[1];
        s16x8 v = { (short)f2bf(a.x), (short)f2bf(a.y), (short)f2bf(a.z), (short)f2bf(a.w),
                    (short)f2bf(b.x), (short)f2bf(b.y), (short)f2bf(b.z), (short)f2bf(b.w) };
        *(s16x8*)(shbuf + row * 128 + ((part ^ (row & 7)) * 16)) = v;
    }
}

template<bool HBF>
__global__ __launch_bounds__(512, 2)
void gru_kernel(const int* __restrict__ ids,
                const unsigned short* __restrict__ mbf,
                const unsigned short* __restrict__ hbf,
                const float* __restrict__ memory,
                const unsigned short* __restrict__ wm,
                const unsigned short* __restrict__ whh,
                const float* __restrict__ wamt,
                const float* __restrict__ bcomb,
                const float* __restrict__ b_hh,
                const float* __restrict__ amt,
                const float* __restrict__ ts,
                float* __restrict__ out_mem,
                float* __restrict__ out_lu,
                int M, int mtiles) {
    extern __shared__ char lds[];
    // layout: sm[2]@0/16384, sh[2]@32768/49152, sw[2]@65536/114688  (=163840 B)

    int g = blockIdx.x;
    int xcd = g & 7, s = g >> 3;
    int nc = s & 3;
    int mtile = (s >> 2) * 8 + xcd;        // 4 nc-blocks of an mtile share one XCD's L2
    if (mtile >= mtiles) return;
    int m0 = mtile * 128;

    int tid = threadIdx.x;
    int lane = tid & 63;
    int w = tid >> 6;
    int wr = w >> 2, wc = w & 3;           // wave = 64 rows x 16 cols

    // prologue: stage chunk 0 into buffer 0
    stage_dma_a(mbf, m0, M, 0, lds, tid);
    if (HBF) stage_dma_a(hbf, m0, M, 0, lds + 32768, tid);
    else     stage_reg_h(ids, memory, m0, M, 0, lds + 32768, tid);
    stage_dma_w(wm, whh, nc, 0, lds + 65536, tid);
    __syncthreads();

    f32x4 acc[6][4];
    #pragma unroll
    for (int pn = 0; pn < 6; ++pn)
        #pragma unroll
        for (int mf = 0; mf < 4; ++mf) acc[pn][mf] = (f32x4){0.f, 0.f, 0.f, 0.f};

    #pragma unroll
    for (int ks = 0; ks < 4; ++ks) {
        char* sm = lds + ((ks & 1) << 14);
        char* sh = lds + 32768 + ((ks & 1) << 14);
        char* sw = lds + 65536 + (ks & 1) * 49152;
        if (ks < 3) {                       // prefetch next chunk into other buffer
            int k0 = (ks + 1) * 64;
            char* smn = lds + (((ks + 1) & 1) << 14);
            char* shn = lds + 32768 + (((ks + 1) & 1) << 14);
            char* swn = lds + 65536 + ((ks + 1) & 1) * 49152;
            stage_dma_a(mbf, m0, M, k0, smn, tid);
            if (HBF) stage_dma_a(hbf, m0, M, k0, shn, tid);
            else     stage_reg_h(ids, memory, m0, M, k0, shn, tid);
            stage_dma_w(wm, whh, nc, k0, swn, tid);
        }
        #pragma unroll
        for (int c = 0; c < 2; ++c) {
            int p = c * 4 + (lane >> 4);
            s16x8 ax[4], ah[4], bw[6];
            #pragma unroll
            for (int mf = 0; mf < 4; ++mf) {
                int row = wr * 64 + mf * 16 + (lane & 15);
                int off = row * 128 + ((p ^ (row & 7)) * 16);
                ax[mf] = *(const s16x8*)(sm + off);
                ah[mf] = *(const s16x8*)(sh + off);
            }
            #pragma unroll
            for (int pn = 0; pn < 6; ++pn) {
                int r = pn * 64 + wc * 16 + (lane & 15);
                bw[pn] = *(const s16x8*)(sw + r * 128 + ((p ^ (r & 7)) * 16));
            }
            #pragma unroll
            for (int pn = 0; pn < 6; ++pn)
                #pragma unroll
                for (int mf = 0; mf < 4; ++mf)
                    acc[pn][mf] = __builtin_amdgcn_mfma_f32_16x16x32_bf16(
                        (pn < 3) ? ax[mf] : ah[mf], bw[pn], acc[pn][mf], 0, 0, 0);
        }
        __syncthreads();                    // drains vmcnt -> next buffers ready
    }

    // epilogue: gates + blend + scatter (lu scatter fused: one thread per row)
    int colL = wc * 16 + (lane & 15);
    int col = nc * 64 + colL;
    float bi0 = bcomb[col], bi1 = bcomb[256 + col], bi2 = bcomb[512 + col];
    float bh0 = b_hh[col],  bh1 = b_hh[256 + col],  bh2 = b_hh[512 + col];
    float wa0 = wamt[col],  wa1 = wamt[256 + col],  wa2 = wamt[512 + col];
    bool lu_thread = (nc == 0) && (colL == 0);
    #pragma unroll
    for (int mf = 0; mf < 4; ++mf) {
        int rb = wr * 64 + mf * 16 + (lane >> 4) * 4;
        #pragma unroll
        for (int r = 0; r < 4; ++r) {
            int grow = m0 + rb + r; if (grow >= M) grow = M - 1;
            int gid = ids[grow];
            float amtv = amt[grow];
            float hv = HBF ? bf2f(hbf[(size_t)grow * 256 + col])
                           : memory[(size_t)gid * 256 + col];
            float ir = acc[0][mf][r] + bi0 + amtv * wa0;
            float iz = acc[1][mf][r] + bi1 + amtv * wa1;
            float in_ = acc[2][mf][r] + bi2 + amtv * wa2;
            float hr = acc[3][mf][r] + bh0;
            float hz = acc[4][mf][r] + bh1;
            float hn = acc[5][mf][r] + bh2;
            float rg = 1.f / (1.f + __expf(-(ir + hr)));
            float zg = 1.f / (1.f + __expf(-(iz + hz)));
            float ng = tanhf(in_ + rg * hn);
            out_mem[(size_t)gid * 256 + col] = (1.f - zg) * ng + zg * hv;
            if (lu_thread) out_lu[gid] = ts[grow];
        }
    }
}

extern "C" void kernel_launch(void* const* d_in, const int* in_sizes, int n_in,
                              void* d_out, int out_size, void* d_ws, size_t ws_size,
                              hipStream_t stream) {
    const int*   ids   = (const int*)  d_in[0];
    const float* msgs  = (const float*)d_in[1];
    const float* ts    = (const float*)d_in[2];
    const float* amt   = (const float*)d_in[3];
    const float* mem   = (const float*)d_in[4];
    const float* lu    = (const float*)d_in[5];
    const float* W_cat = (const float*)d_in[6];
    const float* b_cat = (const float*)d_in[7];
    const float* W_ih  = (const float*)d_in[8];
    const float* W_hh  = (const float*)d_in[9];
    const float* b_ih  = (const float*)d_in[10];
    const float* b_hh  = (const float*)d_in[11];

    int M = in_sizes[0];
    int N = in_sizes[5];

    float* out_mem = (float*)d_out;
    float* out_lu  = out_mem + (size_t)N * 256;

    // ws layout
    char* ws = (char*)d_ws;
    unsigned short* wm    = (unsigned short*)ws;                       // 384 KB
    unsigned short* whh   = wm + 768 * 256;                            // 384 KB
    float*          wamt  = (float*)(whh + 768 * 256);                 // 3 KB
    float*          bcomb = wamt + 768;                                // 3 KB
    int*            inv   = (int*)(bcomb + 768);                       // 4N
    size_t off_mbf = (((char*)(inv + N) - ws) + 15) & ~(size_t)15;
    unsigned short* mbf   = (unsigned short*)(ws + off_mbf);           // 512*M
    unsigned short* hbf   = (unsigned short*)(ws + off_mbf + (size_t)M * 512);
    size_t need_hbf = off_mbf + 2 * (size_t)M * 512;
    bool use_hbf = ws_size >= need_hbf;

    prep_w_kernel<<<(2 * 768 * 256 + 768 + 255) / 256, 256, 0, stream>>>(
        W_cat, b_cat, W_ih, W_hh, b_ih, wm, whh, wamt, bcomb);

    long mchunks = (long)M * 32;           // M*256/8
    long luchunks = N / 4;
    prep_msgs_kernel<<<2048, 256, 0, stream>>>(msgs, mbf, lu, out_lu, mchunks, luchunks);

    (void)hipMemsetAsync(inv, 0, (size_t)N * 4, stream);
    build_inv_kernel<<<(M + 255) / 256, 256, 0, stream>>>(ids, inv, M);

    int mtiles = (M + 127) / 128;
    int mt8 = ((mtiles + 7) / 8) * 8;

    if (use_hbf) {
        copy_gather_kernel<true><<<2048, 256, 0, stream>>>(mem, inv, out_mem, hbf, N);
        (void)hipFuncSetAttribute((const void*)gru_kernel<true>,
                                  hipFuncAttributeMaxDynamicSharedMemorySize, 163840);
        gru_kernel<true><<<mt8 * 4, 512, 163840, stream>>>(
            ids, mbf, hbf, mem, wm, whh, wamt, bcomb, b_hh, amt, ts,
            out_mem, out_lu, M, mtiles);
    } else {
        copy_gather_kernel<false><<<2048, 256, 0, stream>>>(mem, inv, out_mem, hbf, N);
        (void)hipFuncSetAttribute((const void*)gru_kernel<false>,
                                  hipFuncAttributeMaxDynamicSharedMemorySize, 163840);
        gru_kernel<false><<<mt8 * 4, 512, 163840, stream>>>(
            ids, mbf, hbf, mem, wm, whh, wamt, bcomb, b_hh, amt, ts,
            out_mem, out_lu, M, mtiles);
    }
}

// Round 3
// 421.975 us; speedup vs baseline: 1.2331x; 1.0777x over previous
//
#include <hip/hip_runtime.h>
#include <hip/hip_bf16.h>

typedef __attribute__((ext_vector_type(8))) short s16x8;
typedef __attribute__((ext_vector_type(4))) float f32x4;

__device__ __forceinline__ unsigned short f2bf(float x) {
    unsigned int u = __float_as_uint(x);
    u += 0x7fffu + ((u >> 16) & 1u);          // round-to-nearest-even
    return (unsigned short)(u >> 16);
}
__device__ __forceinline__ s16x8 pack8(float4 a, float4 b) {
    return (s16x8){ (short)f2bf(a.x), (short)f2bf(a.y), (short)f2bf(a.z), (short)f2bf(a.w),
                    (short)f2bf(b.x), (short)f2bf(b.y), (short)f2bf(b.z), (short)f2bf(b.w) };
}
__device__ __forceinline__ void gload_lds16(const void* g, void* l) {
    __builtin_amdgcn_global_load_lds(
        (const __attribute__((address_space(1))) void*)g,
        (__attribute__((address_space(3))) void*)(unsigned int)(size_t)l,
        16, 0, 0);
}
__device__ __forceinline__ float sigf(float x) { return 1.f / (1.f + __expf(-x)); }
__device__ __forceinline__ float tanhfast(float x) {
    return 1.f - 2.f / (__expf(2.f * x) + 1.f);
}

// ---------------- prep_w: fold W_cat into W_ih; bf16 weights ----------------
__global__ void prep_w_kernel(const float* __restrict__ W_cat,
                              const float* __restrict__ b_cat,
                              const float* __restrict__ W_ih,
                              const float* __restrict__ W_hh,
                              const float* __restrict__ b_ih,
                              unsigned short* __restrict__ wm,
                              unsigned short* __restrict__ whh,
                              float* __restrict__ wamt,
                              float* __restrict__ bcomb) {
    int idx = blockIdx.x * blockDim.x + threadIdx.x;
    const int NW = 768 * 256;
    if (idx < NW) {
        int g = idx >> 8, c = idx & 255;
        float s = 0.f;
        #pragma unroll 4
        for (int k = 0; k < 256; ++k) s += W_ih[g * 256 + k] * W_cat[k * 257 + c];
        wm[idx] = f2bf(s);
    } else if (idx < 2 * NW) {
        int t = idx - NW;
        whh[t] = f2bf(W_hh[t]);
    } else if (idx < 2 * NW + 768) {
        int g = idx - 2 * NW;
        float sa = 0.f, sb = 0.f;
        for (int k = 0; k < 256; ++k) {
            float w = W_ih[g * 256 + k];
            sa += w * W_cat[k * 257 + 256];
            sb += w * b_cat[k];
        }
        wamt[g] = sa;
        bcomb[g] = sb + b_ih[g];
    }
}

__global__ void build_inv_kernel(const int* __restrict__ ids, int* __restrict__ inv, int M) {
    int i = blockIdx.x * blockDim.x + threadIdx.x;
    if (i < M) inv[ids[i]] = i + 1;
}

// ---------------- fused GRU: gi/gh GEMM + gates + scatter ----------------
// Tile: 128 rows x 64 cols x 6 panels. A (msgs, gathered h) staged from f32
// via reg round-trip (T14 split). Weights DMA'd bf16, double-buffered.
__device__ __forceinline__ void dma_w(const unsigned short* __restrict__ wm,
                                      const unsigned short* __restrict__ whh,
                                      int nc, int k0, char* swbuf, int tid) {
    #pragma unroll
    for (int it = 0; it < 6; ++it) {
        int q = tid + it * 512;
        int r = q >> 3;
        int part = (q & 7) ^ (r & 7);
        int pn = r >> 6, rr = r & 63;
        const unsigned short* src = (pn < 3)
            ? wm  + ((size_t)(pn * 256 + nc * 64 + rr)) * 256
            : whh + ((size_t)((pn - 3) * 256 + nc * 64 + rr)) * 256;
        gload_lds16((const char*)src + k0 * 2 + part * 16,
                    swbuf + (tid & ~63) * 16 + it * 8192);
    }
}

__global__ __launch_bounds__(512, 2)
void gru_kernel(const int* __restrict__ ids,
                const float* __restrict__ msgs,
                const float* __restrict__ memory,
                const unsigned short* __restrict__ wm,
                const unsigned short* __restrict__ whh,
                const float* __restrict__ wamt,
                const float* __restrict__ bcomb,
                const float* __restrict__ b_hh,
                const float* __restrict__ amt,
                float* __restrict__ out_mem,
                int M, int mtiles) {
    extern __shared__ char lds[];
    char* sm  = lds;                 // 16384: msgs slice [128][64 bf16] swizzled
    char* sh  = lds + 16384;         // 16384: h slice
    char* sw0 = lds + 32768;         // 49152: W panels buf 0
    char* sw1 = lds + 81920;         // 49152: W panels buf 1   (total 131072)

    int g = blockIdx.x;
    int xcd = g & 7, s = g >> 3;
    int nc = s & 3;
    int mtile = (s >> 2) * 8 + xcd;  // 4 nc-blocks of one mtile share an XCD L2
    if (mtile >= mtiles) return;
    int m0 = mtile * 128;

    int tid = threadIdx.x;
    int lane = tid & 63;
    int w = tid >> 6;
    int wr = w >> 2, wc = w & 3;     // wave = 64 rows x 16 cols

    // fixed staging coordinates (rows don't change across chunks)
    int row0 = tid >> 3, row1 = (tid + 512) >> 3;
    int part = tid & 7;              // (tid+512)&7 == tid&7
    int gr0 = m0 + row0; if (gr0 >= M) gr0 = M - 1;
    int gr1 = m0 + row1; if (gr1 >= M) gr1 = M - 1;
    const float* mp0 = msgs + (size_t)gr0 * 256 + part * 8;
    const float* mp1 = msgs + (size_t)gr1 * 256 + part * 8;
    const float* hp0 = memory + (size_t)ids[gr0] * 256 + part * 8;
    const float* hp1 = memory + (size_t)ids[gr1] * 256 + part * 8;
    int ld0 = row0 * 128 + ((part ^ (row0 & 7)) * 16);
    int ld1 = row1 * 128 + ((part ^ (row1 & 7)) * 16);

    float4 ma0, mb0, ma1, mb1, ha0, hb0, ha1, hb1;
    // ---- prologue: chunk 0 ----
    {
        ma0 = *(const float4*)(mp0);     mb0 = *(const float4*)(mp0 + 4);
        ma1 = *(const float4*)(mp1);     mb1 = *(const float4*)(mp1 + 4);
        ha0 = *(const float4*)(hp0);     hb0 = *(const float4*)(hp0 + 4);
        ha1 = *(const float4*)(hp1);     hb1 = *(const float4*)(hp1 + 4);
        dma_w(wm, whh, nc, 0, sw0, tid);
        *(s16x8*)(sm + ld0) = pack8(ma0, mb0);
        *(s16x8*)(sm + ld1) = pack8(ma1, mb1);
        *(s16x8*)(sh + ld0) = pack8(ha0, hb0);
        *(s16x8*)(sh + ld1) = pack8(ha1, hb1);
    }
    __syncthreads();                 // drains DMA chunk0 + ds_writes

    f32x4 acc[6][4];
    #pragma unroll
    for (int pn = 0; pn < 6; ++pn)
        #pragma unroll
        for (int mf = 0; mf < 4; ++mf) acc[pn][mf] = (f32x4){0.f, 0.f, 0.f, 0.f};

    #pragma unroll
    for (int ks = 0; ks < 4; ++ks) {
        char* swc = (ks & 1) ? sw1 : sw0;
        if (ks < 3) {                // issue next-chunk loads (latency hides under MFMA)
            int k0 = (ks + 1) * 64;
            ma0 = *(const float4*)(mp0 + k0);  mb0 = *(const float4*)(mp0 + k0 + 4);
            ma1 = *(const float4*)(mp1 + k0);  mb1 = *(const float4*)(mp1 + k0 + 4);
            ha0 = *(const float4*)(hp0 + k0);  hb0 = *(const float4*)(hp0 + k0 + 4);
            ha1 = *(const float4*)(hp1 + k0);  hb1 = *(const float4*)(hp1 + k0 + 4);
            dma_w(wm, whh, nc, k0, (ks & 1) ? sw0 : sw1, tid);
        }
        #pragma unroll
        for (int c = 0; c < 2; ++c) {
            int p = c * 4 + (lane >> 4);
            s16x8 ax[4], ah[4], bw[6];
            #pragma unroll
            for (int mf = 0; mf < 4; ++mf) {
                int row = wr * 64 + mf * 16 + (lane & 15);
                int off = row * 128 + ((p ^ (row & 7)) * 16);
                ax[mf] = *(const s16x8*)(sm + off);
                ah[mf] = *(const s16x8*)(sh + off);
            }
            #pragma unroll
            for (int pn = 0; pn < 6; ++pn) {
                int r = pn * 64 + wc * 16 + (lane & 15);
                bw[pn] = *(const s16x8*)(swc + r * 128 + ((p ^ (r & 7)) * 16));
            }
            #pragma unroll
            for (int pn = 0; pn < 6; ++pn)
                #pragma unroll
                for (int mf = 0; mf < 4; ++mf)
                    acc[pn][mf] = __builtin_amdgcn_mfma_f32_16x16x32_bf16(
                        (pn < 3) ? ax[mf] : ah[mf], bw[pn], acc[pn][mf], 0, 0, 0);
        }
        if (ks < 3) {
            __syncthreads();         // all waves done reading sm/sh; vmcnt drained
            *(s16x8*)(sm + ld0) = pack8(ma0, mb0);
            *(s16x8*)(sm + ld1) = pack8(ma1, mb1);
            *(s16x8*)(sh + ld0) = pack8(ha0, hb0);
            *(s16x8*)(sh + ld1) = pack8(ha1, hb1);
            __syncthreads();
        }
    }

    // ---- epilogue: gates + blend + scatter (lu handled by copy kernel) ----
    int colL = wc * 16 + (lane & 15);
    int col = nc * 64 + colL;
    float bi0 = bcomb[col], bi1 = bcomb[256 + col], bi2 = bcomb[512 + col];
    float bh0 = b_hh[col],  bh1 = b_hh[256 + col],  bh2 = b_hh[512 + col];
    float wa0 = wamt[col],  wa1 = wamt[256 + col],  wa2 = wamt[512 + col];
    #pragma unroll
    for (int mf = 0; mf < 4; ++mf) {
        int rb = wr * 64 + mf * 16 + (lane >> 4) * 4;
        #pragma unroll
        for (int r = 0; r < 4; ++r) {
            int grow = m0 + rb + r; if (grow >= M) grow = M - 1;
            int gid = ids[grow];
            float amtv = amt[grow];
            float hv = memory[(size_t)gid * 256 + col];   // L2-hot (staged above)
            float ir = acc[0][mf][r] + bi0 + amtv * wa0;
            float iz = acc[1][mf][r] + bi1 + amtv * wa1;
            float in_ = acc[2][mf][r] + bi2 + amtv * wa2;
            float hr = acc[3][mf][r] + bh0;
            float hz = acc[4][mf][r] + bh1;
            float hn = acc[5][mf][r] + bh2;
            float rg = sigf(ir + hr);
            float zg = sigf(iz + hz);
            float ng = tanhfast(in_ + rg * hn);
            out_mem[(size_t)gid * 256 + col] = (1.f - zg) * ng + zg * hv;
        }
    }
}

// ---------------- copy: non-updated rows + lu merge, 4-row ILP ----------------
__global__ __launch_bounds__(256)
void copy_kernel(const float* __restrict__ memory,
                 const int* __restrict__ inv,
                 const float* __restrict__ lu,
                 const float* __restrict__ ts,
                 float* __restrict__ out_mem,
                 float* __restrict__ out_lu,
                 int N) {
    int wid = (blockIdx.x * blockDim.x + threadIdx.x) >> 6;
    int lane = threadIdx.x & 63;
    int nw = (gridDim.x * blockDim.x) >> 6;
    for (int base = wid; base < N; base += nw * 4) {
        int  r0 = base, r1 = base + nw, r2 = base + 2 * nw, r3 = base + 3 * nw;
        bool d0 = (r0 < N) && (inv[r0] == 0);
        bool d1 = (r1 < N) && (inv[r1] == 0);
        bool d2 = (r2 < N) && (inv[r2] == 0);
        bool d3 = (r3 < N) && (inv[r3] == 0);
        float4 v0, v1, v2, v3;
        if (d0) v0 = ((const float4*)(memory + (size_t)r0 * 256))[lane];
        if (d1) v1 = ((const float4*)(memory + (size_t)r1 * 256))[lane];
        if (d2) v2 = ((const float4*)(memory + (size_t)r2 * 256))[lane];
        if (d3) v3 = ((const float4*)(memory + (size_t)r3 * 256))[lane];
        if (d0) ((float4*)(out_mem + (size_t)r0 * 256))[lane] = v0;
        if (d1) ((float4*)(out_mem + (size_t)r1 * 256))[lane] = v1;
        if (d2) ((float4*)(out_mem + (size_t)r2 * 256))[lane] = v2;
        if (d3) ((float4*)(out_mem + (size_t)r3 * 256))[lane] = v3;
    }
    // last_update: single pass, no ordering hazard
    int gidx = blockIdx.x * blockDim.x + threadIdx.x;
    int stride = gridDim.x * blockDim.x;
    for (int i = gidx; i < N; i += stride) {
        int iv = inv[i];
        out_lu[i] = iv ? ts[iv - 1] : lu[i];
    }
}

extern "C" void kernel_launch(void* const* d_in, const int* in_sizes, int n_in,
                              void* d_out, int out_size, void* d_ws, size_t ws_size,
                              hipStream_t stream) {
    const int*   ids   = (const int*)  d_in[0];
    const float* msgs  = (const float*)d_in[1];
    const float* ts    = (const float*)d_in[2];
    const float* amt   = (const float*)d_in[3];
    const float* mem   = (const float*)d_in[4];
    const float* lu    = (const float*)d_in[5];
    const float* W_cat = (const float*)d_in[6];
    const float* b_cat = (const float*)d_in[7];
    const float* W_ih  = (const float*)d_in[8];
    const float* W_hh  = (const float*)d_in[9];
    const float* b_ih  = (const float*)d_in[10];
    const float* b_hh  = (const float*)d_in[11];

    int M = in_sizes[0];
    int N = in_sizes[5];

    float* out_mem = (float*)d_out;
    float* out_lu  = out_mem + (size_t)N * 256;

    // ws layout: wm 384KB | whh 384KB | wamt 3KB | bcomb 3KB | inv 4N  (~2.8 MB)
    char* ws = (char*)d_ws;
    unsigned short* wm    = (unsigned short*)ws;
    unsigned short* whh   = wm + 768 * 256;
    float*          wamt  = (float*)(whh + 768 * 256);
    float*          bcomb = wamt + 768;
    int*            inv   = (int*)(bcomb + 768);

    prep_w_kernel<<<(2 * 768 * 256 + 768 + 255) / 256, 256, 0, stream>>>(
        W_cat, b_cat, W_ih, W_hh, b_ih, wm, whh, wamt, bcomb);

    (void)hipMemsetAsync(inv, 0, (size_t)N * 4, stream);
    build_inv_kernel<<<(M + 255) / 256, 256, 0, stream>>>(ids, inv, M);

    int mtiles = (M + 127) / 128;
    int mt8 = ((mtiles + 7) / 8) * 8;
    (void)hipFuncSetAttribute((const void*)gru_kernel,
                              hipFuncAttributeMaxDynamicSharedMemorySize, 131072);
    gru_kernel<<<mt8 * 4, 512, 131072, stream>>>(
        ids, msgs, mem, wm, whh, wamt, bcomb, b_hh, amt, out_mem, M, mtiles);

    copy_kernel<<<2048, 256, 0, stream>>>(mem, inv, lu, ts, out_mem, out_lu, N);
}

// Round 4
// 396.717 us; speedup vs baseline: 1.3116x; 1.0637x over previous
//
#include <hip/hip_runtime.h>
#include <hip/hip_bf16.h>

typedef __attribute__((ext_vector_type(8))) short s16x8;
typedef __attribute__((ext_vector_type(4))) float f32x4;

__device__ __forceinline__ unsigned short f2bf(float x) {
    unsigned int u = __float_as_uint(x);
    u += 0x7fffu + ((u >> 16) & 1u);          // round-to-nearest-even
    return (unsigned short)(u >> 16);
}
__device__ __forceinline__ float bf2f(unsigned short h) {
    return __uint_as_float((unsigned int)h << 16);
}
__device__ __forceinline__ s16x8 pack8(float4 a, float4 b) {
    return (s16x8){ (short)f2bf(a.x), (short)f2bf(a.y), (short)f2bf(a.z), (short)f2bf(a.w),
                    (short)f2bf(b.x), (short)f2bf(b.y), (short)f2bf(b.z), (short)f2bf(b.w) };
}
__device__ __forceinline__ void gload_lds16(const void* g, void* l) {
    __builtin_amdgcn_global_load_lds(
        (const __attribute__((address_space(1))) void*)g,
        (__attribute__((address_space(3))) void*)(unsigned int)(size_t)l,
        16, 0, 0);
}
__device__ __forceinline__ float sigf(float x) { return 1.f / (1.f + __expf(-x)); }
__device__ __forceinline__ float tanhfast(float x) {
    return 1.f - 2.f / (__expf(2.f * x) + 1.f);
}

// ---- prep_w: fold W_cat into W_ih; bf16 weights; + build inv (tail range) ----
__global__ void prep_w_kernel(const float* __restrict__ W_cat,
                              const float* __restrict__ b_cat,
                              const float* __restrict__ W_ih,
                              const float* __restrict__ W_hh,
                              const float* __restrict__ b_ih,
                              const int* __restrict__ ids,
                              unsigned short* __restrict__ wm,
                              unsigned short* __restrict__ whh,
                              float* __restrict__ wamt,
                              float* __restrict__ bcomb,
                              int* __restrict__ inv,
                              int M) {
    int idx = blockIdx.x * blockDim.x + threadIdx.x;
    const int NW = 768 * 256;
    if (idx < NW) {
        int g = idx >> 8, c = idx & 255;
        float s = 0.f;
        #pragma unroll 4
        for (int k = 0; k < 256; ++k) s += W_ih[g * 256 + k] * W_cat[k * 257 + c];
        wm[idx] = f2bf(s);
    } else if (idx < 2 * NW) {
        int t = idx - NW;
        whh[t] = f2bf(W_hh[t]);
    } else if (idx < 2 * NW + 768) {
        int g = idx - 2 * NW;
        float sa = 0.f, sb = 0.f;
        for (int k = 0; k < 256; ++k) {
            float w = W_ih[g * 256 + k];
            sa += w * W_cat[k * 257 + 256];
            sb += w * b_cat[k];
        }
        wamt[g] = sa;
        bcomb[g] = sb + b_ih[g];
    } else if (idx < 2 * NW + 768 + M) {
        int i = idx - (2 * NW + 768);
        inv[ids[i]] = i + 1;                   // inv pre-zeroed by memset
    }
}

// ---------------- fused GRU: gi/gh GEMM + gates + scatter ----------------
// Tile: 128 rows x 64 cols x 6 panels. A (msgs, gathered h) staged from f32
// via reg round-trip (T14 split). Weights DMA'd bf16, double-buffered.
// K-chunks processed in rotated order so chunk `nc` is LAST -> sh still holds
// h[:, nc*64..nc*64+64) at epilogue; hv comes from LDS, not global.
__device__ __forceinline__ void dma_w(const unsigned short* __restrict__ wm,
                                      const unsigned short* __restrict__ whh,
                                      int nc, int k0, char* swbuf, int tid) {
    #pragma unroll
    for (int it = 0; it < 6; ++it) {
        int q = tid + it * 512;
        int r = q >> 3;
        int part = (q & 7) ^ (r & 7);
        int pn = r >> 6, rr = r & 63;
        const unsigned short* src = (pn < 3)
            ? wm  + ((size_t)(pn * 256 + nc * 64 + rr)) * 256
            : whh + ((size_t)((pn - 3) * 256 + nc * 64 + rr)) * 256;
        gload_lds16((const char*)src + k0 * 2 + part * 16,
                    swbuf + (tid & ~63) * 16 + it * 8192);
    }
}

__global__ __launch_bounds__(512, 2)
void gru_kernel(const int* __restrict__ ids,
                const float* __restrict__ msgs,
                const float* __restrict__ memory,
                const unsigned short* __restrict__ wm,
                const unsigned short* __restrict__ whh,
                const float* __restrict__ wamt,
                const float* __restrict__ bcomb,
                const float* __restrict__ b_hh,
                const float* __restrict__ amt,
                float* __restrict__ out_mem,
                int M, int mtiles) {
    extern __shared__ char lds[];
    char* sm  = lds;                 // 16384: msgs slice [128][64 bf16] swizzled
    char* sh  = lds + 16384;         // 16384: h slice
    char* sw0 = lds + 32768;         // 49152: W panels buf 0
    char* sw1 = lds + 81920;         // 49152: W panels buf 1   (total 131072)

    int g = blockIdx.x;
    int xcd = g & 7, s = g >> 3;
    int nc = s & 3;
    int mtile = (s >> 2) * 8 + xcd;  // 4 nc-blocks of one mtile share an XCD L2
    if (mtile >= mtiles) return;
    int m0 = mtile * 128;

    int tid = threadIdx.x;
    int lane = tid & 63;
    int w = tid >> 6;
    int wr = w >> 2, wc = w & 3;     // wave = 64 rows x 16 cols

    // fixed staging coordinates (rows don't change across chunks)
    int row0 = tid >> 3, row1 = (tid + 512) >> 3;
    int part = tid & 7;              // (tid+512)&7 == tid&7
    int gr0 = m0 + row0; if (gr0 >= M) gr0 = M - 1;
    int gr1 = m0 + row1; if (gr1 >= M) gr1 = M - 1;
    const float* mp0 = msgs + (size_t)gr0 * 256 + part * 8;
    const float* mp1 = msgs + (size_t)gr1 * 256 + part * 8;
    const float* hp0 = memory + (size_t)ids[gr0] * 256 + part * 8;
    const float* hp1 = memory + (size_t)ids[gr1] * 256 + part * 8;
    int ld0 = row0 * 128 + ((part ^ (row0 & 7)) * 16);
    int ld1 = row1 * 128 + ((part ^ (row1 & 7)) * 16);

    float4 ma0, mb0, ma1, mb1, ha0, hb0, ha1, hb1;
    // ---- prologue: first chunk in rotated order ----
    {
        int k0 = ((nc + 1) & 3) * 64;
        ma0 = *(const float4*)(mp0 + k0);  mb0 = *(const float4*)(mp0 + k0 + 4);
        ma1 = *(const float4*)(mp1 + k0);  mb1 = *(const float4*)(mp1 + k0 + 4);
        ha0 = *(const float4*)(hp0 + k0);  hb0 = *(const float4*)(hp0 + k0 + 4);
        ha1 = *(const float4*)(hp1 + k0);  hb1 = *(const float4*)(hp1 + k0 + 4);
        dma_w(wm, whh, nc, k0, sw0, tid);
        *(s16x8*)(sm + ld0) = pack8(ma0, mb0);
        *(s16x8*)(sm + ld1) = pack8(ma1, mb1);
        *(s16x8*)(sh + ld0) = pack8(ha0, hb0);
        *(s16x8*)(sh + ld1) = pack8(ha1, hb1);
    }
    __syncthreads();                 // drains DMA chunk + ds_writes

    f32x4 acc[6][4];
    #pragma unroll
    for (int pn = 0; pn < 6; ++pn)
        #pragma unroll
        for (int mf = 0; mf < 4; ++mf) acc[pn][mf] = (f32x4){0.f, 0.f, 0.f, 0.f};

    #pragma unroll
    for (int ks = 0; ks < 4; ++ks) {
        char* swc = (ks & 1) ? sw1 : sw0;
        if (ks < 3) {                // issue next-chunk loads (latency hides under MFMA)
            int k0 = ((nc + 2 + ks) & 3) * 64;       // rotated order, last = nc
            ma0 = *(const float4*)(mp0 + k0);  mb0 = *(const float4*)(mp0 + k0 + 4);
            ma1 = *(const float4*)(mp1 + k0);  mb1 = *(const float4*)(mp1 + k0 + 4);
            ha0 = *(const float4*)(hp0 + k0);  hb0 = *(const float4*)(hp0 + k0 + 4);
            ha1 = *(const float4*)(hp1 + k0);  hb1 = *(const float4*)(hp1 + k0 + 4);
            dma_w(wm, whh, nc, k0, (ks & 1) ? sw0 : sw1, tid);
        }
        #pragma unroll
        for (int c = 0; c < 2; ++c) {
            int p = c * 4 + (lane >> 4);
            s16x8 ax[4], ah[4], bw[6];
            #pragma unroll
            for (int mf = 0; mf < 4; ++mf) {
                int row = wr * 64 + mf * 16 + (lane & 15);
                int off = row * 128 + ((p ^ (row & 7)) * 16);
                ax[mf] = *(const s16x8*)(sm + off);
                ah[mf] = *(const s16x8*)(sh + off);
            }
            #pragma unroll
            for (int pn = 0; pn < 6; ++pn) {
                int r = pn * 64 + wc * 16 + (lane & 15);
                bw[pn] = *(const s16x8*)(swc + r * 128 + ((p ^ (r & 7)) * 16));
            }
            #pragma unroll
            for (int pn = 0; pn < 6; ++pn)
                #pragma unroll
                for (int mf = 0; mf < 4; ++mf)
                    acc[pn][mf] = __builtin_amdgcn_mfma_f32_16x16x32_bf16(
                        (pn < 3) ? ax[mf] : ah[mf], bw[pn], acc[pn][mf], 0, 0, 0);
        }
        if (ks < 3) {
            __syncthreads();         // all waves done reading sm/sh; vmcnt drained
            *(s16x8*)(sm + ld0) = pack8(ma0, mb0);
            *(s16x8*)(sm + ld1) = pack8(ma1, mb1);
            *(s16x8*)(sh + ld0) = pack8(ha0, hb0);
            *(s16x8*)(sh + ld1) = pack8(ha1, hb1);
            __syncthreads();
        }
    }

    // ---- epilogue: gates + blend + scatter; hv from sh (holds chunk nc) ----
    int colL = wc * 16 + (lane & 15);
    int col = nc * 64 + colL;
    float bi0 = bcomb[col], bi1 = bcomb[256 + col], bi2 = bcomb[512 + col];
    float bh0 = b_hh[col],  bh1 = b_hh[256 + col],  bh2 = b_hh[512 + col];
    float wa0 = wamt[col],  wa1 = wamt[256 + col],  wa2 = wamt[512 + col];
    int hpart = colL >> 3, hbyte = (colL & 7) << 1;
    #pragma unroll
    for (int mf = 0; mf < 4; ++mf) {
        int rb = wr * 64 + mf * 16 + (lane >> 4) * 4;
        #pragma unroll
        for (int r = 0; r < 4; ++r) {
            int rl = rb + r;
            int grow = m0 + rl; if (grow >= M) grow = M - 1;
            int gid = ids[grow];
            float amtv = amt[grow];
            float hv = bf2f(*(const unsigned short*)(
                sh + rl * 128 + ((hpart ^ (rl & 7)) << 4) + hbyte));
            float ir = acc[0][mf][r] + bi0 + amtv * wa0;
            float iz = acc[1][mf][r] + bi1 + amtv * wa1;
            float in_ = acc[2][mf][r] + bi2 + amtv * wa2;
            float hr = acc[3][mf][r] + bh0;
            float hz = acc[4][mf][r] + bh1;
            float hn = acc[5][mf][r] + bh2;
            float rg = sigf(ir + hr);
            float zg = sigf(iz + hz);
            float ng = tanhfast(in_ + rg * hn);
            out_mem[(size_t)gid * 256 + col] = (1.f - zg) * ng + zg * hv;
        }
    }
}

// ---------------- copy: non-updated rows + lu merge, 4-row ILP ----------------
__global__ __launch_bounds__(256)
void copy_kernel(const float* __restrict__ memory,
                 const int* __restrict__ inv,
                 const float* __restrict__ lu,
                 const float* __restrict__ ts,
                 float* __restrict__ out_mem,
                 float* __restrict__ out_lu,
                 int N) {
    int wid = (blockIdx.x * blockDim.x + threadIdx.x) >> 6;
    int lane = threadIdx.x & 63;
    int nw = (gridDim.x * blockDim.x) >> 6;
    for (int base = wid; base < N; base += nw * 4) {
        int  r0 = base, r1 = base + nw, r2 = base + 2 * nw, r3 = base + 3 * nw;
        bool d0 = (r0 < N) && (inv[r0] == 0);
        bool d1 = (r1 < N) && (inv[r1] == 0);
        bool d2 = (r2 < N) && (inv[r2] == 0);
        bool d3 = (r3 < N) && (inv[r3] == 0);
        float4 v0, v1, v2, v3;
        if (d0) v0 = ((const float4*)(memory + (size_t)r0 * 256))[lane];
        if (d1) v1 = ((const float4*)(memory + (size_t)r1 * 256))[lane];
        if (d2) v2 = ((const float4*)(memory + (size_t)r2 * 256))[lane];
        if (d3) v3 = ((const float4*)(memory + (size_t)r3 * 256))[lane];
        if (d0) ((float4*)(out_mem + (size_t)r0 * 256))[lane] = v0;
        if (d1) ((float4*)(out_mem + (size_t)r1 * 256))[lane] = v1;
        if (d2) ((float4*)(out_mem + (size_t)r2 * 256))[lane] = v2;
        if (d3) ((float4*)(out_mem + (size_t)r3 * 256))[lane] = v3;
    }
    // last_update: single pass, no ordering hazard (inv/lu/ts L2-hot)
    int gidx = blockIdx.x * blockDim.x + threadIdx.x;
    int stride = gridDim.x * blockDim.x;
    for (int i = gidx; i < N; i += stride) {
        int iv = inv[i];
        out_lu[i] = iv ? ts[iv - 1] : lu[i];
    }
}

extern "C" void kernel_launch(void* const* d_in, const int* in_sizes, int n_in,
                              void* d_out, int out_size, void* d_ws, size_t ws_size,
                              hipStream_t stream) {
    const int*   ids   = (const int*)  d_in[0];
    const float* msgs  = (const float*)d_in[1];
    const float* ts    = (const float*)d_in[2];
    const float* amt   = (const float*)d_in[3];
    const float* mem   = (const float*)d_in[4];
    const float* lu    = (const float*)d_in[5];
    const float* W_cat = (const float*)d_in[6];
    const float* b_cat = (const float*)d_in[7];
    const float* W_ih  = (const float*)d_in[8];
    const float* W_hh  = (const float*)d_in[9];
    const float* b_ih  = (const float*)d_in[10];
    const float* b_hh  = (const float*)d_in[11];

    int M = in_sizes[0];
    int N = in_sizes[5];

    float* out_mem = (float*)d_out;
    float* out_lu  = out_mem + (size_t)N * 256;

    // ws layout: wm 384KB | whh 384KB | wamt 3KB | bcomb 3KB | inv 4N  (~2.8 MB)
    char* ws = (char*)d_ws;
    unsigned short* wm    = (unsigned short*)ws;
    unsigned short* whh   = wm + 768 * 256;
    float*          wamt  = (float*)(whh + 768 * 256);
    float*          bcomb = wamt + 768;
    int*            inv   = (int*)(bcomb + 768);

    (void)hipMemsetAsync(inv, 0, (size_t)N * 4, stream);

    int prep_items = 2 * 768 * 256 + 768 + M;
    prep_w_kernel<<<(prep_items + 255) / 256, 256, 0, stream>>>(
        W_cat, b_cat, W_ih, W_hh, b_ih, ids, wm, whh, wamt, bcomb, inv, M);

    int mtiles = (M + 127) / 128;
    int mt8 = ((mtiles + 7) / 8) * 8;
    (void)hipFuncSetAttribute((const void*)gru_kernel,
                              hipFuncAttributeMaxDynamicSharedMemorySize, 131072);
    gru_kernel<<<mt8 * 4, 512, 131072, stream>>>(
        ids, msgs, mem, wm, whh, wamt, bcomb, b_hh, amt, out_mem, M, mtiles);

    copy_kernel<<<2048, 256, 0, stream>>>(mem, inv, lu, ts, out_mem, out_lu, N);
}